// Round 6
// baseline (9174.881 us; speedup 1.0000x reference)
//
#include <hip/hip_runtime.h>
#include <hip/hip_bf16.h>

// AKT_27917287424232 — 3-block distance-decay attention transformer.
// B=8, S=1024, D=512, H=8, dk=64.
// RESOLVED (rounds 0-5): inputs fp32, OUTPUTS FP32 (d_out = float*,
// 3*BSD elements in return order: out, hq, hs). The earlier bf16-output
// assumption glued bf16 pairs into fp32 on readback -> constant 6.52 absmax.
//
// Workspace: 3 fp32 BSD buffers (48 MiB). hq/hs live in their d_out slots
// (fp32) and are re-read in block 3; block-3 'o' staged in the out slot
// before the final GEMM overwrites it.

typedef __hip_bfloat16 bf16;

constexpr int Bn = 8, Sn = 1024, Dn = 512, Hn = 8, DKn = 64;
constexpr float LN_EPS = 1e-5f;

__device__ inline float wave_reduce_sum(float v) {
    #pragma unroll
    for (int off = 32; off; off >>= 1) v += __shfl_xor(v, off, 64);
    return v;
}
__device__ inline float wave_reduce_max(float v) {
    #pragma unroll
    for (int off = 32; off; off >>= 1) v = fmaxf(v, __shfl_xor(v, off, 64));
    return v;
}
// Block of exactly 256 threads (4 waves). smem >= 4 floats.
__device__ inline float block_reduce_sum(float v, float* smem) {
    int lane = threadIdx.x & 63, wave = threadIdx.x >> 6;
    v = wave_reduce_sum(v);
    __syncthreads();
    if (lane == 0) smem[wave] = v;
    __syncthreads();
    return smem[0] + smem[1] + smem[2] + smem[3];
}
__device__ inline float block_reduce_max(float v, float* smem) {
    int lane = threadIdx.x & 63, wave = threadIdx.x >> 6;
    v = wave_reduce_max(v);
    __syncthreads();
    if (lane == 0) smem[wave] = v;
    __syncthreads();
    return fmaxf(fmaxf(smem[0], smem[1]), fmaxf(smem[2], smem[3]));
}

// ---------------------------------------------------------------------------
// C[M,N] = A[M,K] @ W[K,N] + bias[N]. 64x64 tile, BK=16, 4x4/thread. fp32.
// ---------------------------------------------------------------------------
__global__ __launch_bounds__(256) void gemm_bias(
    const float* __restrict__ A, const float* __restrict__ W,
    const float* __restrict__ bias, float* __restrict__ C, int M, int N,
    int K) {
    __shared__ __align__(16) float As[16][68];
    __shared__ __align__(16) float Bs[16][68];
    const int bm = blockIdx.y * 64, bn = blockIdx.x * 64;
    const int tid = threadIdx.x;
    const int tx = tid & 15, ty = tid >> 4;
    float acc[4][4] = {};
    for (int k0 = 0; k0 < K; k0 += 16) {
        #pragma unroll
        for (int l = 0; l < 4; l++) {
            int idx = tid + l * 256;
            int m = idx >> 4, kk = idx & 15;
            As[kk][m] = A[(size_t)(bm + m) * K + k0 + kk];
        }
        #pragma unroll
        for (int l = 0; l < 4; l++) {
            int idx = tid + l * 256;
            int kk = idx >> 6, n = idx & 63;
            Bs[kk][n] = W[(size_t)(k0 + kk) * N + bn + n];
        }
        __syncthreads();
        #pragma unroll
        for (int kk = 0; kk < 16; kk++) {
            float4 a4 = *reinterpret_cast<const float4*>(&As[kk][ty * 4]);
            float4 b4 = *reinterpret_cast<const float4*>(&Bs[kk][tx * 4]);
            float a[4] = {a4.x, a4.y, a4.z, a4.w};
            float b[4] = {b4.x, b4.y, b4.z, b4.w};
            #pragma unroll
            for (int um = 0; um < 4; um++)
                #pragma unroll
                for (int un = 0; un < 4; un++) acc[um][un] += a[um] * b[un];
        }
        __syncthreads();
    }
    #pragma unroll
    for (int um = 0; um < 4; um++) {
        int m = bm + ty * 4 + um;
        #pragma unroll
        for (int un = 0; un < 4; un++) {
            int n = bn + tx * 4 + un;
            C[(size_t)m * N + n] = acc[um][un] + bias[n];
        }
    }
}

// out[M,512] = [A1 | A2][M,1024] @ W[1024,512] + bias[512], fp32 out.
__global__ __launch_bounds__(256) void gemm_cat(
    const float* __restrict__ A1, const float* __restrict__ A2,
    const float* __restrict__ W, const float* __restrict__ bias,
    float* __restrict__ C, int M, int N) {
    __shared__ __align__(16) float As[16][68];
    __shared__ __align__(16) float Bs[16][68];
    const int bm = blockIdx.y * 64, bn = blockIdx.x * 64;
    const int tid = threadIdx.x;
    const int tx = tid & 15, ty = tid >> 4;
    float acc[4][4] = {};
    const int K = 2 * Dn;
    for (int k0 = 0; k0 < K; k0 += 16) {
        const float* A = (k0 < Dn) ? A1 : A2;
        const int kc = k0 & (Dn - 1);
        #pragma unroll
        for (int l = 0; l < 4; l++) {
            int idx = tid + l * 256;
            int m = idx >> 4, kk = idx & 15;
            As[kk][m] = A[(size_t)(bm + m) * Dn + kc + kk];
        }
        #pragma unroll
        for (int l = 0; l < 4; l++) {
            int idx = tid + l * 256;
            int kk = idx >> 6, n = idx & 63;
            Bs[kk][n] = W[(size_t)(k0 + kk) * N + bn + n];
        }
        __syncthreads();
        #pragma unroll
        for (int kk = 0; kk < 16; kk++) {
            float4 a4 = *reinterpret_cast<const float4*>(&As[kk][ty * 4]);
            float4 b4 = *reinterpret_cast<const float4*>(&Bs[kk][tx * 4]);
            float a[4] = {a4.x, a4.y, a4.z, a4.w};
            float b[4] = {b4.x, b4.y, b4.z, b4.w};
            #pragma unroll
            for (int um = 0; um < 4; um++)
                #pragma unroll
                for (int un = 0; un < 4; un++) acc[um][un] += a[um] * b[un];
        }
        __syncthreads();
    }
    #pragma unroll
    for (int um = 0; um < 4; um++) {
        int m = bm + ty * 4 + um;
        #pragma unroll
        for (int un = 0; un < 4; un++) {
            int n = bn + tx * 4 + un;
            C[(size_t)m * N + n] = acc[um][un] + bias[n];
        }
    }
}

// ---------------------------------------------------------------------------
// Distance-decay attention, one workgroup (256 thr) per (b,h,i) row.
// MODE: 0 = j<=i; 1 = j<i; 2 = i-19<=j<i. All fp32.
// a = softmax2( (masked s) * clamp(exp(-|g|*sqrt((1-cumsum(p1))*(i-j))),1e-5,1e5) )
// MAXOUT: a *= min(1/max(a),5) == min(Z2,5)/Z2 since max(a)=1/Z2.
// ---------------------------------------------------------------------------
template <int MODE, bool MAXOUT>
__global__ __launch_bounds__(256) void attn_kernel(
    const float* __restrict__ QK, const float* __restrict__ V,
    const float* __restrict__ gam, size_t g_off, float* __restrict__ O) {
    __shared__ float s_row[Sn];
    __shared__ float p_row[Sn];
    __shared__ float part[256];
    __shared__ float red[4];

    const int idx = blockIdx.x;
    const int i = idx & (Sn - 1);
    const int bh = idx >> 10;
    const int h = bh & (Hn - 1);
    const int b = bh >> 3;
    const int jlo = (MODE == 2) ? max(0, i - 19) : 0;
    const int jhi = (MODE == 0) ? (i + 1) : i;

    const int tid = threadIdx.x;
    const int lane = tid & 63;
    const int wave = tid >> 6;

    const float* Qrow = QK + ((size_t)(b * Sn + i)) * Dn + h * DKn;
    float* Orow = O + ((size_t)(b * Sn + i)) * Dn + h * DKn;

    if (jhi <= jlo) {  // fully masked row -> a == 0 -> zero output
        if (tid < DKn) Orow[tid] = 0.f;
        return;
    }

    const float* Kbase = QK + (size_t)b * Sn * Dn + h * DKn;
    const float* Vbase = V + (size_t)b * Sn * Dn + h * DKn;
    const float q = Qrow[lane];

    // Pass 1: s[j] = (q . k_j)/8, one wave per j (lane = d).
    for (int j = jlo + wave; j < jhi; j += 4) {
        float pr = q * Kbase[(size_t)j * Dn + lane];
        pr = wave_reduce_sum(pr);
        if (lane == 0) s_row[j] = pr * 0.125f;
    }
    for (int j = tid; j < Sn; j += 256) p_row[j] = 0.f;
    __syncthreads();

    // Softmax #1 -> unnormalized exp in p_row (zeros outside mask).
    float lmax = -3.4e38f;
    for (int j = jlo + tid; j < jhi; j += 256) lmax = fmaxf(lmax, s_row[j]);
    const float m1 = block_reduce_max(lmax, red);
    for (int j = jlo + tid; j < jhi; j += 256) p_row[j] = expf(s_row[j] - m1);
    __syncthreads();

    // Inclusive cumsum over full 1024 via LDS Hillis-Steele on 256 partials.
    const int base = tid * 4;
    const float x0 = p_row[base], x1 = p_row[base + 1], x2 = p_row[base + 2],
                x3 = p_row[base + 3];
    const float t1 = x0 + x1, t2 = t1 + x2, t3 = t2 + x3;
    part[tid] = t3;
    __syncthreads();
    #pragma unroll
    for (int off = 1; off < 256; off <<= 1) {
        float add = (tid >= off) ? part[tid - off] : 0.f;
        __syncthreads();
        part[tid] += add;
        __syncthreads();
    }
    const float Z1 = part[255];
    const float excl = part[tid] - t3;
    p_row[base] = excl + x0;
    p_row[base + 1] = excl + t1;
    p_row[base + 2] = excl + t2;
    p_row[base + 3] = excl + t3;
    __syncthreads();

    // Distance-decay rescale.
    const float g = -fabsf(gam[g_off + h]);
    const float invZ1 = 1.f / Z1;
    for (int j = jlo + tid; j < jhi; j += 256) {
        float cum = p_row[j] * invZ1;
        float dist = sqrtf(fmaxf((1.f - cum) * (float)(i - j), 0.f));
        float decay = fminf(fmaxf(expf(g * dist), 1e-5f), 1e5f);
        s_row[j] = s_row[j] * decay;
    }

    // Softmax #2 (+ maxout).
    float lmax2 = -3.4e38f;
    for (int j = jlo + tid; j < jhi; j += 256) lmax2 = fmaxf(lmax2, s_row[j]);
    const float m2 = block_reduce_max(lmax2, red);
    float lsum = 0.f;
    for (int j = jlo + tid; j < jhi; j += 256) {
        float e = expf(s_row[j] - m2);
        p_row[j] = e;
        lsum += e;
    }
    const float Z2 = block_reduce_sum(lsum, red);
    float coef = 1.f / Z2;
    if (MAXOUT) coef *= fminf(Z2, 5.f);

    // out[d] = coef * sum_j e_j * V[j,d].
    float acc = 0.f;
    for (int j = jlo + wave; j < jhi; j += 4) {
        acc += p_row[j] * Vbase[(size_t)j * Dn + lane];
    }
    acc *= coef;
    __syncthreads();
    s_row[wave * 64 + lane] = acc;
    __syncthreads();
    if (wave == 0) {
        Orow[lane] = s_row[lane] + s_row[64 + lane] + s_row[128 + lane] +
                     s_row[192 + lane];
    }
}

// ---------------------------------------------------------------------------
// out = LN(x + y) (fp32), one block per row of D=512.
// ---------------------------------------------------------------------------
__global__ __launch_bounds__(256) void add_ln(
    const float* __restrict__ X, const float* __restrict__ Y,
    const float* __restrict__ lnw, const float* __restrict__ lnb, size_t off,
    float* __restrict__ out) {
    __shared__ float red[4];
    const int row = blockIdx.x, tid = threadIdx.x;
    const size_t base = (size_t)row * Dn;
    float v0 = X[base + tid] + Y[base + tid];
    float v1 = X[base + tid + 256] + Y[base + tid + 256];
    const float mu = block_reduce_sum(v0 + v1, red) * (1.f / Dn);
    const float d0 = v0 - mu, d1 = v1 - mu;
    const float var = block_reduce_sum(d0 * d0 + d1 * d1, red) * (1.f / Dn);
    const float rs = rsqrtf(var + LN_EPS);
    out[base + tid] = d0 * rs * lnw[off + tid] + lnb[off + tid];
    out[base + tid + 256] = d1 * rs * lnw[off + tid + 256] + lnb[off + tid + 256];
}

// ---------------------------------------------------------------------------
// catA = LN2(hq + o); catB = LN2(hq + o + ow). All fp32, disjoint buffers.
// ---------------------------------------------------------------------------
__global__ __launch_bounds__(256) void cat_ln(
    const float* __restrict__ hq, const float* __restrict__ o,
    const float* __restrict__ ow, const float* __restrict__ lnw,
    const float* __restrict__ lnb, size_t off, float* __restrict__ catA,
    float* __restrict__ catB) {
    __shared__ float red[4];
    const int row = blockIdx.x, tid = threadIdx.x;
    const size_t base = (size_t)row * Dn;
    const float h0 = hq[base + tid] + o[base + tid];
    const float h1 = hq[base + tid + 256] + o[base + tid + 256];
    const float hw0 = h0 + ow[base + tid];
    const float hw1 = h1 + ow[base + tid + 256];
    const float w0 = lnw[off + tid], w1 = lnw[off + tid + 256];
    const float b0 = lnb[off + tid], b1 = lnb[off + tid + 256];

    float mu = block_reduce_sum(h0 + h1, red) * (1.f / Dn);
    float d0 = h0 - mu, d1 = h1 - mu;
    float var = block_reduce_sum(d0 * d0 + d1 * d1, red) * (1.f / Dn);
    float rs = rsqrtf(var + LN_EPS);
    catA[base + tid] = d0 * rs * w0 + b0;
    catA[base + tid + 256] = d1 * rs * w1 + b1;

    mu = block_reduce_sum(hw0 + hw1, red) * (1.f / Dn);
    d0 = hw0 - mu;
    d1 = hw1 - mu;
    var = block_reduce_sum(d0 * d0 + d1 * d1, red) * (1.f / Dn);
    rs = rsqrtf(var + LN_EPS);
    catB[base + tid] = d0 * rs * w0 + b0;
    catB[base + tid + 256] = d1 * rs * w1 + b1;
}

extern "C" void kernel_launch(void* const* d_in, const int* in_sizes, int n_in,
                              void* d_out, int out_size, void* d_ws,
                              size_t ws_size, hipStream_t stream) {
    const float* q_emb = (const float*)d_in[0];
    const float* s_emb = (const float*)d_in[1];
    const float* Wq = (const float*)d_in[2];
    const float* bq = (const float*)d_in[3];
    const float* Wqw = (const float*)d_in[4];
    const float* bqw = (const float*)d_in[5];
    const float* Wv = (const float*)d_in[6];
    const float* bv = (const float*)d_in[7];
    const float* Wo = (const float*)d_in[8];
    const float* bo = (const float*)d_in[9];
    const float* Wow = (const float*)d_in[10];
    const float* bow = (const float*)d_in[11];
    const float* gammas = (const float*)d_in[12];
    const float* ln_w = (const float*)d_in[13];
    const float* ln_b = (const float*)d_in[14];
    const float* Wc = (const float*)d_in[15];
    const float* bc = (const float*)d_in[16];
    // d_in[17] = lens: unused in the forward pass.

    const size_t BSD = (size_t)Bn * Sn * Dn;
    float* ws = (float*)d_ws;
    float* W0 = ws;
    float* W1 = ws + BSD;
    float* W2 = ws + 2 * BSD;

    float* out_main = (float*)d_out;          // out  [B,S,D] fp32
    float* out_hq = out_main + BSD;           // hq   [B,S,D] fp32
    float* out_hs = out_main + 2 * BSD;       // hs   [B,S,D] fp32

    const int rows = Bn * Sn;  // 8192
    const dim3 tpb(256);
    const dim3 ggemm(Dn / 64, rows / 64);
    const dim3 gattn(Bn * Hn * Sn);
    const dim3 grow(rows);
    const size_t DD = (size_t)Dn * Dn;

    // ---- Block 1: hq = LN0(q_emb + attn0(q_emb)) -> out_hq ----
    gemm_bias<<<ggemm, tpb, 0, stream>>>(q_emb, Wq, bq, W0, rows, Dn, Dn);
    gemm_bias<<<ggemm, tpb, 0, stream>>>(q_emb, Wv, bv, W1, rows, Dn, Dn);
    attn_kernel<0, false><<<gattn, tpb, 0, stream>>>(W0, W1, gammas, 0, W2);
    gemm_bias<<<ggemm, tpb, 0, stream>>>(W2, Wo, bo, W0, rows, Dn, Dn);
    add_ln<<<grow, tpb, 0, stream>>>(q_emb, W0, ln_w, ln_b, 0, out_hq);

    // ---- Block 2: hs = LN1(s_emb + attn1(s_emb)) -> out_hs ----
    gemm_bias<<<ggemm, tpb, 0, stream>>>(s_emb, Wq + DD, bq + Dn, W0, rows, Dn, Dn);
    gemm_bias<<<ggemm, tpb, 0, stream>>>(s_emb, Wv + DD, bv + Dn, W1, rows, Dn, Dn);
    attn_kernel<0, false><<<gattn, tpb, 0, stream>>>(W0, W1, gammas, Hn, W2);
    gemm_bias<<<ggemm, tpb, 0, stream>>>(W2, Wo + DD, bo + Dn, W0, rows, Dn, Dn);
    add_ln<<<grow, tpb, 0, stream>>>(s_emb, W0, ln_w, ln_b, Dn, out_hs);

    // ---- Block 3: xq=xk=hq, xv=hs ----
    // q3 -> W0 ; v3 -> W1
    gemm_bias<<<ggemm, tpb, 0, stream>>>(out_hq, Wq + 2 * DD, bq + 2 * Dn, W0, rows, Dn, Dn);
    gemm_bias<<<ggemm, tpb, 0, stream>>>(out_hs, Wv + 2 * DD, bv + 2 * Dn, W1, rows, Dn, Dn);
    // a3 (strict mask + maxout) -> W2
    attn_kernel<1, true><<<gattn, tpb, 0, stream>>>(W0, W1, gammas, 2 * Hn, W2);
    // o = a3 @ Wo[2] + bo[2] -> staged in out_main (fp32 scratch until final)
    gemm_bias<<<ggemm, tpb, 0, stream>>>(W2, Wo + 2 * DD, bo + 2 * Dn, out_main, rows, Dn, Dn);
    // qw -> W0 (q3 dead)
    gemm_bias<<<ggemm, tpb, 0, stream>>>(out_hq, Wqw + 2 * DD, bqw + 2 * Dn, W0, rows, Dn, Dn);
    // aw (window) -> W2 (a3 dead)
    attn_kernel<2, false><<<gattn, tpb, 0, stream>>>(W0, W1, gammas, 2 * Hn, W2);
    // ow = aw @ Wow + bow -> W0 (qw dead)
    gemm_bias<<<ggemm, tpb, 0, stream>>>(W2, Wow, bow, W0, rows, Dn, Dn);
    // catA = LN2(hq + o) -> W1 (v3 dead); catB = LN2(hq + o + ow) -> W2
    cat_ln<<<grow, tpb, 0, stream>>>(out_hq, out_main, W0, ln_w, ln_b, 2 * Dn, W1, W2);
    // out = [catA | catB] @ Wc + bc -> out_main (overwrites o staging)
    gemm_cat<<<ggemm, tpb, 0, stream>>>(W1, W2, Wc, bc, out_main, rows, Dn);
}

// Round 7
// 4214.830 us; speedup vs baseline: 2.1768x; 2.1768x over previous
//
#include <hip/hip_runtime.h>
#include <hip/hip_bf16.h>

// AKT_27917287424232 — 3-block distance-decay attention transformer.
// B=8, S=1024, D=512, H=8, dk=64. Inputs fp32, outputs fp32 (out,hq,hs).
// R7: tiled attention rewrite (8 query rows/block, LDS K/V tiles, register
// blocking) replacing the per-row wave_reduce kernel (was 2.9 ms/dispatch).

typedef __hip_bfloat16 bf16;

constexpr int Bn = 8, Sn = 1024, Dn = 512, Hn = 8, DKn = 64;
constexpr float LN_EPS = 1e-5f;
constexpr int TQ = 8;    // query rows per block
constexpr int TJ = 128;  // K/V tile rows
constexpr int KS = 66;   // LDS row stride for q/k/v tiles (2-way max aliasing)

__device__ inline float wave_reduce_sum(float v) {
    #pragma unroll
    for (int off = 32; off; off >>= 1) v += __shfl_xor(v, off, 64);
    return v;
}
// Block of exactly 256 threads (4 waves). smem >= 4 floats.
__device__ inline float block_reduce_sum(float v, float* smem) {
    int lane = threadIdx.x & 63, wave = threadIdx.x >> 6;
    v = wave_reduce_sum(v);
    __syncthreads();
    if (lane == 0) smem[wave] = v;
    __syncthreads();
    return smem[0] + smem[1] + smem[2] + smem[3];
}

// ---------------------------------------------------------------------------
// C[M,N] = A[M,K] @ W[K,N] + bias[N]. 64x64 tile, BK=16, 4x4/thread. fp32.
// ---------------------------------------------------------------------------
__global__ __launch_bounds__(256) void gemm_bias(
    const float* __restrict__ A, const float* __restrict__ W,
    const float* __restrict__ bias, float* __restrict__ C, int M, int N,
    int K) {
    __shared__ __align__(16) float As[16][68];
    __shared__ __align__(16) float Bs[16][68];
    const int bm = blockIdx.y * 64, bn = blockIdx.x * 64;
    const int tid = threadIdx.x;
    const int tx = tid & 15, ty = tid >> 4;
    float acc[4][4] = {};
    for (int k0 = 0; k0 < K; k0 += 16) {
        #pragma unroll
        for (int l = 0; l < 4; l++) {
            int idx = tid + l * 256;
            int m = idx >> 4, kk = idx & 15;
            As[kk][m] = A[(size_t)(bm + m) * K + k0 + kk];
        }
        #pragma unroll
        for (int l = 0; l < 4; l++) {
            int idx = tid + l * 256;
            int kk = idx >> 6, n = idx & 63;
            Bs[kk][n] = W[(size_t)(k0 + kk) * N + bn + n];
        }
        __syncthreads();
        #pragma unroll
        for (int kk = 0; kk < 16; kk++) {
            float4 a4 = *reinterpret_cast<const float4*>(&As[kk][ty * 4]);
            float4 b4 = *reinterpret_cast<const float4*>(&Bs[kk][tx * 4]);
            float a[4] = {a4.x, a4.y, a4.z, a4.w};
            float b[4] = {b4.x, b4.y, b4.z, b4.w};
            #pragma unroll
            for (int um = 0; um < 4; um++)
                #pragma unroll
                for (int un = 0; un < 4; un++) acc[um][un] += a[um] * b[un];
        }
        __syncthreads();
    }
    #pragma unroll
    for (int um = 0; um < 4; um++) {
        int m = bm + ty * 4 + um;
        #pragma unroll
        for (int un = 0; un < 4; un++) {
            int n = bn + tx * 4 + un;
            C[(size_t)m * N + n] = acc[um][un] + bias[n];
        }
    }
}

// out[M,512] = [A1 | A2][M,1024] @ W[1024,512] + bias[512], fp32 out.
__global__ __launch_bounds__(256) void gemm_cat(
    const float* __restrict__ A1, const float* __restrict__ A2,
    const float* __restrict__ W, const float* __restrict__ bias,
    float* __restrict__ C, int M, int N) {
    __shared__ __align__(16) float As[16][68];
    __shared__ __align__(16) float Bs[16][68];
    const int bm = blockIdx.y * 64, bn = blockIdx.x * 64;
    const int tid = threadIdx.x;
    const int tx = tid & 15, ty = tid >> 4;
    float acc[4][4] = {};
    const int K = 2 * Dn;
    for (int k0 = 0; k0 < K; k0 += 16) {
        const float* A = (k0 < Dn) ? A1 : A2;
        const int kc = k0 & (Dn - 1);
        #pragma unroll
        for (int l = 0; l < 4; l++) {
            int idx = tid + l * 256;
            int m = idx >> 4, kk = idx & 15;
            As[kk][m] = A[(size_t)(bm + m) * Dn + kc + kk];
        }
        #pragma unroll
        for (int l = 0; l < 4; l++) {
            int idx = tid + l * 256;
            int kk = idx >> 6, n = idx & 63;
            Bs[kk][n] = W[(size_t)(k0 + kk) * N + bn + n];
        }
        __syncthreads();
        #pragma unroll
        for (int kk = 0; kk < 16; kk++) {
            float4 a4 = *reinterpret_cast<const float4*>(&As[kk][ty * 4]);
            float4 b4 = *reinterpret_cast<const float4*>(&Bs[kk][tx * 4]);
            float a[4] = {a4.x, a4.y, a4.z, a4.w};
            float b[4] = {b4.x, b4.y, b4.z, b4.w};
            #pragma unroll
            for (int um = 0; um < 4; um++)
                #pragma unroll
                for (int un = 0; un < 4; un++) acc[um][un] += a[um] * b[un];
        }
        __syncthreads();
    }
    #pragma unroll
    for (int um = 0; um < 4; um++) {
        int m = bm + ty * 4 + um;
        #pragma unroll
        for (int un = 0; un < 4; un++) {
            int n = bn + tx * 4 + un;
            C[(size_t)m * N + n] = acc[um][un] + bias[n];
        }
    }
}

// ---------------------------------------------------------------------------
// Tiled distance-decay attention. One block (256 thr) per (b,h, 8-row tile).
// MODE: 0 = j<=i; 1 = j<i; 2 = i-19<=j<i.
// Phases: stage Q; per K-tile(128): stage K, compute scores (2x2 reg block);
// per-row softmax1 (32 thr/row, half-wave shuffles + 32-wide scan), cumsum,
// decay rescale; softmax2 (+maxout coef); per V-tile: stage V, accumulate A.V
// (4-wave j-split, 2x4 reg block); combine partials, scale by coef, store.
// ---------------------------------------------------------------------------
template <int MODE, bool MAXOUT>
__global__ __launch_bounds__(256) void attn_tile(
    const float* __restrict__ QK, const float* __restrict__ V,
    const float* __restrict__ gam, size_t g_off, float* __restrict__ O) {
    __shared__ float q_t[TQ * KS];               // 2112 B
    __shared__ float kv[TJ * KS];                // 33792 B (K then V)
    __shared__ float s_t[TQ * Sn];               // 32768 B (scores->s'->e)
    __shared__ float part[256];                  // 1024 B (scan)
    __shared__ __align__(16) float pv[4 * 512];  // 8192 B (A.V partials)
    __shared__ float rcoef[TQ];

    const int tid = threadIdx.x;
    const int i0 = blockIdx.x * TQ;
    const int bh = blockIdx.y;
    const int h = bh & (Hn - 1);
    const int b = bh >> 3;

    const float* Kbase = QK + (size_t)b * Sn * Dn + h * DKn;  // Q==K buffer
    const float* Vbase = V + (size_t)b * Sn * Dn + h * DKn;

    const int last_j = (MODE == 0) ? (i0 + TQ - 1) : (i0 + TQ - 2);
    const int jt_hi = (last_j >> 7) + 1;
    const int jt_lo = (MODE == 2) ? (max(0, i0 - 19) >> 7) : 0;

    // ---- stage Q (8 rows x 64) ----
    #pragma unroll
    for (int rep = 0; rep < 2; rep++) {
        int idx = tid + rep * 256;
        int r = idx >> 6, d = idx & 63;
        q_t[r * KS + d] = Kbase[(size_t)(i0 + r) * Dn + d];
    }

    // ---- phase 1: scores ----
    const int pc = tid & 63;
    const int pr = tid >> 6;  // wave id -> rows 2pr, 2pr+1
    const int r0 = 2 * pr, r1 = r0 + 1;
    for (int jt = jt_lo; jt < jt_hi; jt++) {
        __syncthreads();
        #pragma unroll
        for (int rep = 0; rep < 8; rep++) {
            int f = rep * 1024 + tid * 4;
            int row = f >> 6, d = f & 63;
            const float4 v4 = *reinterpret_cast<const float4*>(
                &Kbase[(size_t)(jt * TJ + row) * Dn + d]);
            float* dst = &kv[row * KS + d];
            *reinterpret_cast<float2*>(dst) = make_float2(v4.x, v4.y);
            *reinterpret_cast<float2*>(dst + 2) = make_float2(v4.z, v4.w);
        }
        __syncthreads();
        float d00 = 0.f, d01 = 0.f, d10 = 0.f, d11 = 0.f;
        #pragma unroll 8
        for (int d = 0; d < DKn; d += 2) {
            float2 qa = *reinterpret_cast<const float2*>(&q_t[r0 * KS + d]);
            float2 qb = *reinterpret_cast<const float2*>(&q_t[r1 * KS + d]);
            float2 ka = *reinterpret_cast<const float2*>(&kv[pc * KS + d]);
            float2 kb = *reinterpret_cast<const float2*>(&kv[(pc + 64) * KS + d]);
            d00 += qa.x * ka.x + qa.y * ka.y;
            d01 += qa.x * kb.x + qa.y * kb.y;
            d10 += qb.x * ka.x + qb.y * ka.y;
            d11 += qb.x * kb.x + qb.y * kb.y;
        }
        const int ja = jt * TJ + pc, jb = ja + 64;
        s_t[r0 * Sn + ja] = d00 * 0.125f;
        s_t[r0 * Sn + jb] = d01 * 0.125f;
        s_t[r1 * Sn + ja] = d10 * 0.125f;
        s_t[r1 * Sn + jb] = d11 * 0.125f;
    }
    __syncthreads();

    // ---- phases 2-4: per-row softmax1 / cumsum / decay / softmax2 ----
    const int sr = tid >> 5, st = tid & 31;  // 8 rows x 32 threads
    const int i = i0 + sr;
    float* srow = &s_t[sr * Sn];
    const int c0 = st * 32, c1 = c0 + 32;
    #define VALIDJ(j) (MODE == 0 ? ((j) <= i) \
                      : (MODE == 1 ? ((j) < i) : (((j) < i) && ((j) >= i - 19))))

    float lm = -3.4e38f;
    for (int j = c0; j < c1; j++)
        if (VALIDJ(j)) lm = fmaxf(lm, srow[j]);
    #pragma unroll
    for (int off = 16; off; off >>= 1) lm = fmaxf(lm, __shfl_xor(lm, off, 64));
    const float m1 = lm;

    float csum = 0.f;
    for (int j = c0; j < c1; j++)
        csum += VALIDJ(j) ? expf(srow[j] - m1) : 0.f;
    part[tid] = csum;
    __syncthreads();
    #pragma unroll
    for (int off = 1; off < 32; off <<= 1) {
        float add = (st >= off) ? part[tid - off] : 0.f;
        __syncthreads();
        part[tid] += add;
        __syncthreads();
    }
    const float Z1 = part[sr * 32 + 31];
    const float invZ1 = 1.f / fmaxf(Z1, 1e-37f);
    const float g = -fabsf(gam[g_off + h]);
    float run = part[tid] - csum;  // exclusive prefix at chunk start
    for (int j = c0; j < c1; j++) {
        if (VALIDJ(j)) {
            float s = srow[j];
            float p = expf(s - m1);
            run += p;
            float cum = run * invZ1;
            float dist = sqrtf(fmaxf((1.f - cum) * (float)(i - j), 0.f));
            float decay = fminf(fmaxf(expf(g * dist), 1e-5f), 1e5f);
            srow[j] = s * decay;
        }
    }

    float lm2 = -3.4e38f;
    for (int j = c0; j < c1; j++)
        if (VALIDJ(j)) lm2 = fmaxf(lm2, srow[j]);
    #pragma unroll
    for (int off = 16; off; off >>= 1) lm2 = fmaxf(lm2, __shfl_xor(lm2, off, 64));
    float z2c = 0.f;
    for (int j = c0; j < c1; j++) {
        float e = VALIDJ(j) ? expf(srow[j] - lm2) : 0.f;
        srow[j] = e;
        z2c += e;
    }
    #pragma unroll
    for (int off = 16; off; off >>= 1) z2c += __shfl_xor(z2c, off, 64);
    if (st == 0)
        rcoef[sr] = (MAXOUT ? fminf(z2c, 5.f) : 1.f) / fmaxf(z2c, 1e-37f);
    #undef VALIDJ

    // ---- phase 5: A.V (wave w handles 32 j's per tile) ----
    const int w = tid >> 6, lane = tid & 63;
    const int gq = lane >> 4, lt = lane & 15;
    const int ar0 = 2 * gq, ar1 = ar0 + 1;
    float a0[4] = {0.f, 0.f, 0.f, 0.f}, a1[4] = {0.f, 0.f, 0.f, 0.f};
    for (int jt = jt_lo; jt < jt_hi; jt++) {
        __syncthreads();
        #pragma unroll
        for (int rep = 0; rep < 8; rep++) {
            int f = rep * 1024 + tid * 4;
            int row = f >> 6, d = f & 63;
            const float4 v4 = *reinterpret_cast<const float4*>(
                &Vbase[(size_t)(jt * TJ + row) * Dn + d]);
            float* dst = &kv[row * KS + d];
            *reinterpret_cast<float2*>(dst) = make_float2(v4.x, v4.y);
            *reinterpret_cast<float2*>(dst + 2) = make_float2(v4.z, v4.w);
        }
        __syncthreads();
        const int jbase = w * 32;
        #pragma unroll 4
        for (int jj = 0; jj < 32; jj++) {
            int j = jbase + jj;
            int gj = jt * TJ + j;
            float e0 = s_t[ar0 * Sn + gj];
            float e1 = s_t[ar1 * Sn + gj];
            float2 va = *reinterpret_cast<const float2*>(&kv[j * KS + 4 * lt]);
            float2 vb = *reinterpret_cast<const float2*>(&kv[j * KS + 4 * lt + 2]);
            a0[0] += e0 * va.x; a0[1] += e0 * va.y;
            a0[2] += e0 * vb.x; a0[3] += e0 * vb.y;
            a1[0] += e1 * va.x; a1[1] += e1 * va.y;
            a1[2] += e1 * vb.x; a1[3] += e1 * vb.y;
        }
    }
    *reinterpret_cast<float4*>(&pv[w * 512 + ar0 * 64 + 4 * lt]) =
        make_float4(a0[0], a0[1], a0[2], a0[3]);
    *reinterpret_cast<float4*>(&pv[w * 512 + ar1 * 64 + 4 * lt]) =
        make_float4(a1[0], a1[1], a1[2], a1[3]);
    __syncthreads();

    // ---- combine + store ----
    #pragma unroll
    for (int rep = 0; rep < 2; rep++) {
        int idx = tid + rep * 256;
        int r = idx >> 6, d = idx & 63;
        float v = (pv[idx] + pv[512 + idx] + pv[1024 + idx] + pv[1536 + idx]) *
                  rcoef[r];
        O[(size_t)(b * Sn + i0 + r) * Dn + h * DKn + d] = v;
    }
}

// ---------------------------------------------------------------------------
// out = LN(x + y) (fp32), one block per row of D=512.
// ---------------------------------------------------------------------------
__global__ __launch_bounds__(256) void add_ln(
    const float* __restrict__ X, const float* __restrict__ Y,
    const float* __restrict__ lnw, const float* __restrict__ lnb, size_t off,
    float* __restrict__ out) {
    __shared__ float red[4];
    const int row = blockIdx.x, tid = threadIdx.x;
    const size_t base = (size_t)row * Dn;
    float v0 = X[base + tid] + Y[base + tid];
    float v1 = X[base + tid + 256] + Y[base + tid + 256];
    const float mu = block_reduce_sum(v0 + v1, red) * (1.f / Dn);
    const float d0 = v0 - mu, d1 = v1 - mu;
    const float var = block_reduce_sum(d0 * d0 + d1 * d1, red) * (1.f / Dn);
    const float rs = rsqrtf(var + LN_EPS);
    out[base + tid] = d0 * rs * lnw[off + tid] + lnb[off + tid];
    out[base + tid + 256] = d1 * rs * lnw[off + tid + 256] + lnb[off + tid + 256];
}

// ---------------------------------------------------------------------------
// catA = LN2(hq + o); catB = LN2(hq + o + ow). All fp32, disjoint buffers.
// ---------------------------------------------------------------------------
__global__ __launch_bounds__(256) void cat_ln(
    const float* __restrict__ hq, const float* __restrict__ o,
    const float* __restrict__ ow, const float* __restrict__ lnw,
    const float* __restrict__ lnb, size_t off, float* __restrict__ catA,
    float* __restrict__ catB) {
    __shared__ float red[4];
    const int row = blockIdx.x, tid = threadIdx.x;
    const size_t base = (size_t)row * Dn;
    const float h0 = hq[base + tid] + o[base + tid];
    const float h1 = hq[base + tid + 256] + o[base + tid + 256];
    const float hw0 = h0 + ow[base + tid];
    const float hw1 = h1 + ow[base + tid + 256];
    const float w0 = lnw[off + tid], w1 = lnw[off + tid + 256];
    const float b0 = lnb[off + tid], b1 = lnb[off + tid + 256];

    float mu = block_reduce_sum(h0 + h1, red) * (1.f / Dn);
    float d0 = h0 - mu, d1 = h1 - mu;
    float var = block_reduce_sum(d0 * d0 + d1 * d1, red) * (1.f / Dn);
    float rs = rsqrtf(var + LN_EPS);
    catA[base + tid] = d0 * rs * w0 + b0;
    catA[base + tid + 256] = d1 * rs * w1 + b1;

    mu = block_reduce_sum(hw0 + hw1, red) * (1.f / Dn);
    d0 = hw0 - mu;
    d1 = hw1 - mu;
    var = block_reduce_sum(d0 * d0 + d1 * d1, red) * (1.f / Dn);
    rs = rsqrtf(var + LN_EPS);
    catB[base + tid] = d0 * rs * w0 + b0;
    catB[base + tid + 256] = d1 * rs * w1 + b1;
}

extern "C" void kernel_launch(void* const* d_in, const int* in_sizes, int n_in,
                              void* d_out, int out_size, void* d_ws,
                              size_t ws_size, hipStream_t stream) {
    const float* q_emb = (const float*)d_in[0];
    const float* s_emb = (const float*)d_in[1];
    const float* Wq = (const float*)d_in[2];
    const float* bq = (const float*)d_in[3];
    const float* Wqw = (const float*)d_in[4];
    const float* bqw = (const float*)d_in[5];
    const float* Wv = (const float*)d_in[6];
    const float* bv = (const float*)d_in[7];
    const float* Wo = (const float*)d_in[8];
    const float* bo = (const float*)d_in[9];
    const float* Wow = (const float*)d_in[10];
    const float* bow = (const float*)d_in[11];
    const float* gammas = (const float*)d_in[12];
    const float* ln_w = (const float*)d_in[13];
    const float* ln_b = (const float*)d_in[14];
    const float* Wc = (const float*)d_in[15];
    const float* bc = (const float*)d_in[16];
    // d_in[17] = lens: unused in the forward pass.

    const size_t BSD = (size_t)Bn * Sn * Dn;
    float* ws = (float*)d_ws;
    float* W0 = ws;
    float* W1 = ws + BSD;
    float* W2 = ws + 2 * BSD;

    float* out_main = (float*)d_out;     // out [B,S,D]
    float* out_hq = out_main + BSD;      // hq
    float* out_hs = out_main + 2 * BSD;  // hs

    const int rows = Bn * Sn;  // 8192
    const dim3 tpb(256);
    const dim3 ggemm(Dn / 64, rows / 64);
    const dim3 gattn(Sn / TQ, Bn * Hn);  // (128, 64)
    const dim3 grow(rows);
    const size_t DD = (size_t)Dn * Dn;

    // ---- Block 1: hq = LN0(q_emb + attn0(q_emb)) -> out_hq ----
    gemm_bias<<<ggemm, tpb, 0, stream>>>(q_emb, Wq, bq, W0, rows, Dn, Dn);
    gemm_bias<<<ggemm, tpb, 0, stream>>>(q_emb, Wv, bv, W1, rows, Dn, Dn);
    attn_tile<0, false><<<gattn, tpb, 0, stream>>>(W0, W1, gammas, 0, W2);
    gemm_bias<<<ggemm, tpb, 0, stream>>>(W2, Wo, bo, W0, rows, Dn, Dn);
    add_ln<<<grow, tpb, 0, stream>>>(q_emb, W0, ln_w, ln_b, 0, out_hq);

    // ---- Block 2: hs = LN1(s_emb + attn1(s_emb)) -> out_hs ----
    gemm_bias<<<ggemm, tpb, 0, stream>>>(s_emb, Wq + DD, bq + Dn, W0, rows, Dn, Dn);
    gemm_bias<<<ggemm, tpb, 0, stream>>>(s_emb, Wv + DD, bv + Dn, W1, rows, Dn, Dn);
    attn_tile<0, false><<<gattn, tpb, 0, stream>>>(W0, W1, gammas, Hn, W2);
    gemm_bias<<<ggemm, tpb, 0, stream>>>(W2, Wo + DD, bo + Dn, W0, rows, Dn, Dn);
    add_ln<<<grow, tpb, 0, stream>>>(s_emb, W0, ln_w, ln_b, Dn, out_hs);

    // ---- Block 3: xq=xk=hq, xv=hs ----
    gemm_bias<<<ggemm, tpb, 0, stream>>>(out_hq, Wq + 2 * DD, bq + 2 * Dn, W0, rows, Dn, Dn);
    gemm_bias<<<ggemm, tpb, 0, stream>>>(out_hs, Wv + 2 * DD, bv + 2 * Dn, W1, rows, Dn, Dn);
    attn_tile<1, true><<<gattn, tpb, 0, stream>>>(W0, W1, gammas, 2 * Hn, W2);
    gemm_bias<<<ggemm, tpb, 0, stream>>>(W2, Wo + 2 * DD, bo + 2 * Dn, out_main, rows, Dn, Dn);
    gemm_bias<<<ggemm, tpb, 0, stream>>>(out_hq, Wqw + 2 * DD, bqw + 2 * Dn, W0, rows, Dn, Dn);
    attn_tile<2, false><<<gattn, tpb, 0, stream>>>(W0, W1, gammas, 2 * Hn, W2);
    gemm_bias<<<ggemm, tpb, 0, stream>>>(W2, Wow, bow, W0, rows, Dn, Dn);
    // catA = LN2(hq + o) -> W1 ; catB = LN2(hq + o + ow) -> W2
    cat_ln<<<grow, tpb, 0, stream>>>(out_hq, out_main, W0, ln_w, ln_b, 2 * Dn, W1, W2);
    gemm_cat<<<ggemm, tpb, 0, stream>>>(W1, W2, Wc, bc, out_main, rows, Dn);
}